// Round 2
// baseline (108.917 us; speedup 1.0000x reference)
//
#include <hip/hip_runtime.h>
#include <hip/hip_bf16.h>

// Modulated conv2d (StyleGAN2) on MI355X.
// out[b,o] = rsig[b,o] * conv(s[b,:]*x[b,:], W*SCALE)   (shared weights)
// rsig[b,o] = 1/sqrt(sum_i s[b,i]^2 * wsq[o,i] + 1e-8)
// Conv as implicit GEMM: D[o][p] = sum_k Wb[o][k] * Xcl[p][k],
//   k = tap*512 + ci, Xcl = channels-last halo-padded input (zero halo).
//
// R2: conv GEMM rewritten from m97-structure (2-barrier, vmcnt drain; 846 TF)
// to counted-vmcnt phased schedule (T3+T4+T5): BM=128 x BN=256, BK=64,
// 512 thr / 8 waves (2x4), TRIPLE-buffered LDS (144 KiB) so staging runs
// 2 K-tiles ahead -> per-tile wait is vmcnt(6), never 0. 2 phases/K-tile,
// 16 MFMA/phase wrapped in setprio(1), raw s_barrier (no __syncthreads drain).

typedef __attribute__((ext_vector_type(4))) float f32x4;
typedef __attribute__((ext_vector_type(8))) short bf16x8;

#define NB    16
#define CIN   512
#define COUT  512
#define KTOT  4608           // CIN * 9
#define NPIX  (NB * 32 * 32) // 16384
#define BUFELEM 24576        // (128*64 + 256*64) bf16 elements per LDS buffer

#define WAITV6() asm volatile("s_waitcnt vmcnt(6)" ::: "memory")
#define WAITV0() asm volatile("s_waitcnt vmcnt(0)" ::: "memory")
#define FENCE()  asm volatile("" ::: "memory")
#define BAR()    { FENCE(); __builtin_amdgcn_s_barrier(); FENCE(); }

__device__ __forceinline__ void gload_lds16(const void* g, void* l) {
  __builtin_amdgcn_global_load_lds(
      (__attribute__((address_space(1))) void*)(g),
      (__attribute__((address_space(3))) void*)(l), 16, 0, 0);
}

// ---------------- kernel 1: pack weights (bf16, [o][tap*512+ci]) + wsq ----------------
__global__ __launch_bounds__(256) void pack_w_kernel(
    const float* __restrict__ w, __hip_bfloat16* __restrict__ wB,
    float* __restrict__ wsq) {
  const int idx = blockIdx.x * 256 + threadIdx.x;   // = o*512 + ci
  const int o = idx >> 9, ci = idx & 511;
  const float* wp = w + (size_t)idx * 9;
  const float WSCALE = 0.014731391274719739f;       // 1/sqrt(512*9)
  float sum = 0.f;
#pragma unroll
  for (int t = 0; t < 9; ++t) {
    float v = wp[t] * WSCALE;
    sum += v * v;
    wB[(size_t)o * KTOT + t * 512 + ci] = __float2bfloat16(v);
  }
  wsq[idx] = sum;
}

// ---------------- kernel 2: rsig[b][o], one wave per (b,o) ----------------
__global__ __launch_bounds__(256) void calc_rsig_kernel(
    const float* __restrict__ s, const float* __restrict__ wsq,
    float* __restrict__ rsig) {
  const int wid = blockIdx.x * 4 + (threadIdx.x >> 6); // b*512 + o
  const int lane = threadIdx.x & 63;
  const int b = wid >> 9, o = wid & 511;
  const float* sp = s + b * 512;
  const float* wp = wsq + o * 512;
  float sum = 0.f;
#pragma unroll
  for (int i = 0; i < 8; ++i) {
    float sv = sp[lane + i * 64];
    sum += sv * sv * wp[lane + i * 64];
  }
#pragma unroll
  for (int off = 32; off > 0; off >>= 1) sum += __shfl_down(sum, off, 64);
  if (lane == 0) rsig[wid] = 1.0f / sqrtf(sum + 1e-8f);
}

// ---------------- kernel 3: modulate + NCHW->padded channels-last bf16 ----------------
__global__ __launch_bounds__(256) void modulate_kernel(
    const float* __restrict__ x, const float* __restrict__ s,
    __hip_bfloat16* __restrict__ xpad) {
  const int by = blockIdx.x;            // b*32 + y
  const int b = by >> 5, y = by & 31;
  __shared__ __attribute__((aligned(16))) __hip_bfloat16 tile[32][72];
  const int tid = threadIdx.x;
  const int xc = tid & 31;
  const int cr0 = tid >> 5;             // 0..7
  const float* xrow = x + ((size_t)b * 512 * 32 + y) * 32; // + ci*1024 + xc
  const float* sb = s + b * 512;
  __hip_bfloat16* orow = xpad + (size_t)((b * 34 + y + 1) * 34) * 512;

  for (int ci0 = 0; ci0 < 512; ci0 += 64) {
#pragma unroll
    for (int r = 0; r < 8; ++r) {
      const int cir = r * 8 + cr0;
      const int ci = ci0 + cir;
      float v = xrow[(size_t)ci * 1024 + xc] * sb[ci];
      tile[xc][cir] = __float2bfloat16(v);
    }
    __syncthreads();
    const int xcw = tid >> 3, vec = tid & 7;
    bf16x8 v = *(const bf16x8*)&tile[xcw][vec * 8];
    *(bf16x8*)(orow + (size_t)(xcw + 1) * 512 + ci0 + vec * 8) = v;
    __syncthreads();
  }
}

// ---------------- kernel 4: implicit-GEMM conv, counted-vmcnt phased ----------------
// LDS buffer i (i=0..2): A = lds + i*BUFELEM (128 rows x 64 bf16),
//                        B = lds + i*BUFELEM + 8192 (256 rows x 64 bf16).
// Row-major, 128 B/row, XOR swizzle byte ^= ((row&7)<<4) on BOTH the staging
// global source chunk and the ds_read address (rule 21). 0 bank conflicts (R1).
__global__ __launch_bounds__(512, 1) void conv_gemm_kernel(
    const __hip_bfloat16* __restrict__ wB,    // [512][4608]
    const __hip_bfloat16* __restrict__ xpad,  // [16][34][34][512]
    const float* __restrict__ rsig,           // [16][512]
    float* __restrict__ out) {                // [16][512][32][32]
  extern __shared__ __attribute__((aligned(16))) __hip_bfloat16 lds[];

  const int tid = threadIdx.x;
  const int wv = tid >> 6, lane = tid & 63;
  const int bo0 = blockIdx.y << 7;   // cout block (128)
  const int bp0 = blockIdx.x << 8;   // pixel block (256; 256 | 1024 per image)
  const int wr = wv >> 2, wc = wv & 3;   // wave grid 2(M) x 4(N)

  // Staging source offsets (loop-invariant part). Round r = 512 threads x 16B.
  int gA[2];   // element offset in wB; add kt*64 per tile
#pragma unroll
  for (int r = 0; r < 2; ++r) {
    const int c = r * 512 + tid, row = c >> 3, sc = (c & 7) ^ (row & 7);
    gA[r] = (bo0 + row) * KTOT + sc * 8;
  }
  int gB[4];   // element offset in xpad; add tapoff*512 + ci0 per tile
#pragma unroll
  for (int r = 0; r < 4; ++r) {
    const int c = r * 512 + tid, row = c >> 3, sc = (c & 7) ^ (row & 7);
    const int p = bp0 + row, b = p >> 10, rem = p & 1023, y = rem >> 5,
              xx = rem & 31;
    gB[r] = ((b * 34 + y) * 34 + xx) * 512 + sc * 8;
  }

  auto stageA = [&](int kt2, int r) {
    __hip_bfloat16* dst = lds + (kt2 % 3) * BUFELEM + (size_t)(r * 512 + (wv << 6)) * 8;
    gload_lds16(wB + (size_t)(gA[r] + (kt2 << 6)), dst);
  };
  auto stageB = [&](int kt2, int r, int xoff) {
    __hip_bfloat16* dst = lds + (kt2 % 3) * BUFELEM + 8192 + (size_t)(r * 512 + (wv << 6)) * 8;
    gload_lds16(xpad + (size_t)(gB[r] + xoff), dst);
  };

  f32x4 acc[4][4];
#pragma unroll
  for (int mi = 0; mi < 4; ++mi)
#pragma unroll
    for (int ni = 0; ni < 4; ++ni) acc[mi][ni] = f32x4{0.f, 0.f, 0.f, 0.f};

  // Prologue: fully stage tiles 0 and 1 (6 vmem ops each).
  stageA(0, 0); stageA(0, 1);
  stageB(0, 0, 0); stageB(0, 1, 0); stageB(0, 2, 0); stageB(0, 3, 0);
  stageA(1, 0); stageA(1, 1);
  stageB(1, 0, 64); stageB(1, 1, 64); stageB(1, 2, 64); stageB(1, 3, 64);
  WAITV6();      // tile 0's 6 oldest done; tile 1's 6 still in flight
  BAR();

  for (int kt = 0; kt < 72; ++kt) {
    const __hip_bfloat16* bufA = lds + (kt % 3) * BUFELEM;
    const __hip_bfloat16* bufB = bufA + 8192;
    const int kt2 = kt + 2;
    const bool pf = kt2 < 72;
    int xoff = 0;
    if (pf) {
      const int tap = kt2 >> 3, ty = (tap * 11) >> 5;  // tap/3 for tap<9
      xoff = (tap + 31 * ty) * 512 + ((kt2 & 7) << 6); // tapoff*512 + ci0
    }

    // ---- phase 0: k-step 0 (bytes 0..63 of each row pair-half) ----
    {
      bf16x8 af[4], bv[4];
      const int kb = (lane >> 4) << 4;
#pragma unroll
      for (int mi = 0; mi < 4; ++mi) {
        const int row = (wr << 6) + (mi << 4) + (lane & 15);
        af[mi] = *(const bf16x8*)((const char*)bufA + row * 128 +
                                  (kb ^ ((row & 7) << 4)));
      }
#pragma unroll
      for (int ni = 0; ni < 4; ++ni) {
        const int row = (wc << 6) + (ni << 4) + (lane & 15);
        bv[ni] = *(const bf16x8*)((const char*)bufB + row * 128 +
                                  (kb ^ ((row & 7) << 4)));
      }
      if (pf) { stageA(kt2, 0); stageA(kt2, 1); stageB(kt2, 0, xoff); }
      BAR();
      __builtin_amdgcn_s_setprio(1);
#pragma unroll
      for (int mi = 0; mi < 4; ++mi)
#pragma unroll
        for (int ni = 0; ni < 4; ++ni)
          acc[mi][ni] = __builtin_amdgcn_mfma_f32_16x16x32_bf16(
              af[mi], bv[ni], acc[mi][ni], 0, 0, 0);
      __builtin_amdgcn_s_setprio(0);
      BAR();
    }

    // ---- phase 1: k-step 1 ----
    {
      bf16x8 af[4], bv[4];
      const int kb = 64 + ((lane >> 4) << 4);
#pragma unroll
      for (int mi = 0; mi < 4; ++mi) {
        const int row = (wr << 6) + (mi << 4) + (lane & 15);
        af[mi] = *(const bf16x8*)((const char*)bufA + row * 128 +
                                  (kb ^ ((row & 7) << 4)));
      }
#pragma unroll
      for (int ni = 0; ni < 4; ++ni) {
        const int row = (wc << 6) + (ni << 4) + (lane & 15);
        bv[ni] = *(const bf16x8*)((const char*)bufB + row * 128 +
                                  (kb ^ ((row & 7) << 4)));
      }
      if (pf) { stageB(kt2, 1, xoff); stageB(kt2, 2, xoff); stageB(kt2, 3, xoff); }
      BAR();
      __builtin_amdgcn_s_setprio(1);
#pragma unroll
      for (int mi = 0; mi < 4; ++mi)
#pragma unroll
        for (int ni = 0; ni < 4; ++ni)
          acc[mi][ni] = __builtin_amdgcn_mfma_f32_16x16x32_bf16(
              af[mi], bv[ni], acc[mi][ni], 0, 0, 0);
      __builtin_amdgcn_s_setprio(0);
      // Closing wait: tile kt+1's loads must be done. Outstanding beyond them:
      // tile kt+2's 6 (if staged this iter) -> vmcnt(6); kt==70 -> vmcnt(0).
      if (kt < 70) { WAITV6(); } else if (kt == 70) { WAITV0(); }
      BAR();
    }
  }

  // Epilogue: D[o][p] * rsig[b][o]. C/D: col(=p)=lane&15, row(=o)=(lane>>4)*4+r
  const int bimg = bp0 >> 10;
#pragma unroll
  for (int mi = 0; mi < 4; ++mi) {
    const int o = bo0 + (wr << 6) + (mi << 4) + ((lane >> 4) << 2);
    const f32x4 rs = *(const f32x4*)(rsig + (bimg << 9) + o);
#pragma unroll
    for (int ni = 0; ni < 4; ++ni) {
      const int p = bp0 + (wc << 6) + (ni << 4) + (lane & 15);
      const int prem = p & 1023;
#pragma unroll
      for (int r = 0; r < 4; ++r)
        out[((size_t)(bimg << 9) + o + r) * 1024 + prem] =
            acc[mi][ni][r] * rs[r];
    }
  }
}

extern "C" void kernel_launch(void* const* d_in, const int* in_sizes, int n_in,
                              void* d_out, int out_size, void* d_ws,
                              size_t ws_size, hipStream_t stream) {
  const float* x = (const float*)d_in[0];   // [16,512,32,32]
  const float* s = (const float*)d_in[1];   // [16,512]
  const float* w = (const float*)d_in[2];   // [512,512,3,3]
  float* out = (float*)d_out;               // [16,512,32,32] f32

  char* ws = (char*)d_ws;
  const size_t xpad_bytes = (size_t)NB * 34 * 34 * 512 * 2;  // 18,939,904
  const size_t wB_bytes = (size_t)COUT * KTOT * 2;           //  4,718,592
  const size_t wsq_bytes = (size_t)COUT * CIN * 4;           //  1,048,576
  __hip_bfloat16* xpad = (__hip_bfloat16*)ws;
  __hip_bfloat16* wB = (__hip_bfloat16*)(ws + xpad_bytes);
  float* wsq = (float*)(ws + xpad_bytes + wB_bytes);
  float* rsig = (float*)(ws + xpad_bytes + wB_bytes + wsq_bytes);

  const int lds_bytes = 3 * BUFELEM * 2;   // 147456 B = 144 KiB
  hipFuncSetAttribute((const void*)conv_gemm_kernel,
                      hipFuncAttributeMaxDynamicSharedMemorySize, lds_bytes);

  hipMemsetAsync(xpad, 0, xpad_bytes, stream);  // zero halo (capturable)
  pack_w_kernel<<<(COUT * CIN) / 256, 256, 0, stream>>>(w, wB, wsq);
  modulate_kernel<<<NB * 32, 256, 0, stream>>>(x, s, xpad);
  calc_rsig_kernel<<<(NB * COUT) / 4, 256, 0, stream>>>(s, wsq, rsig);
  conv_gemm_kernel<<<dim3(NPIX / 256, COUT / 128), 512, lds_bytes, stream>>>(
      wB, xpad, rsig, out);
}